// Round 10
// baseline (127.687 us; speedup 1.0000x reference)
//
#include <hip/hip_runtime.h>
#include <hip/hip_bf16.h>
#include <math.h>

// Symmetric Hausdorff, B=8, N=M=4096, D=2, fp32.
// Round 10: single kernel, atomic-only funnel. R6's fusion died because 1024
// device fences sat on 8 MB of dirty plain stores (pw -> HBM writeback storm).
// Here the cross-block data path is ONLY device-scope atomics: each block
// atomicMin's its per-i partial mins (int bits; positive floats are
// int-monotone) into a 256 KB pmin array — nothing dirty at fence time, so
// the lane-0 __threadfence per block is cheap (R8 evidence). Group (dir,b) =
// 64 blocks; the 64th block max-reduces its group's 4096 entries (read via
// returning atomics — immune to XCD L2 staleness), publishes a slot, and the
// 16th group-last computes the final scalar. Partial loop = R5's exact code
// (measured balance point: LDS broadcast pipe ~80 cyc/window vs 84 cyc VALU;
// R7's pk packing was LDS-capped, R9's IB=16 lost occupancy).
// pmin init = 0x7F7F7F7F (+3.39e38, > any d^2); counters init = 0.
// The ~43us fillBuffer in every profile is the harness poisoning the 256 MiB
// workspace inside the timed window — fixed cost, not ours.

#define B 8
#define N 4096
#define TPB 256
#define IB 8              // i-points per thread
#define JC 32             // j-chunks per (b,dir)
#define JTILE (N / JC)    // 128 j-points per block
#define GBLOCKS 64        // blocks per (dir,b) group: 2 ib-halves x 32 jc
#define NGROUP 16         // (dir,b) groups

__global__ __launch_bounds__(TPB) void hk_main(const float* __restrict__ pred,
                                               const float* __restrict__ target,
                                               int* __restrict__ pmin,   // [2][B][N] int-bits
                                               int* __restrict__ cnt,    // [16]
                                               int* __restrict__ slots,  // [16]
                                               int* __restrict__ cnt2,   // [1]
                                               float* __restrict__ out) {
    const int bx  = blockIdx.x;        // 0..63: [ib: bit0] x [jc: bits1..5]
    const int ib  = bx & 1;
    const int jc  = bx >> 1;
    const int b   = blockIdx.y;
    const int dir = blockIdx.z;
    const int t   = threadIdx.x;
    const int g   = dir * B + b;       // group id

    __shared__ float4 sQ[JTILE / 2];
    __shared__ float  sred[TPB / 64];
    __shared__ int    sflag, sflag2;

    const float2* __restrict__ P =
        reinterpret_cast<const float2*>(dir == 0 ? pred : target) + (size_t)b * N;
    const float*  __restrict__ Qf =
        (dir == 0 ? target : pred) + (size_t)b * N * 2 + (size_t)jc * JTILE * 2;

    // ---- Stage 1: R5's exact partial-min loop ----
    if (t < JTILE / 2)
        sQ[t] = reinterpret_cast<const float4*>(Qf)[t];
    __syncthreads();

    float m2x[IB], m2y[IB], pp[IB], mn[IB];
    const int i0 = ib * (TPB * IB) + t;
    #pragma unroll
    for (int k = 0; k < IB; ++k) {
        float2 p = P[i0 + k * TPB];
        m2x[k] = -2.f * p.x;
        m2y[k] = -2.f * p.y;
        pp[k]  = fmaf(p.x, p.x, p.y * p.y);
        mn[k]  = 3.402823466e38f;
    }

    #pragma unroll 4
    for (int j = 0; j < JTILE / 2; ++j) {
        float4 q = sQ[j];
        float qqa = fmaf(q.x, q.x, q.y * q.y);
        float qqb = fmaf(q.z, q.z, q.w * q.w);
        #pragma unroll
        for (int k = 0; k < IB; ++k) {
            float ta = fmaf(m2x[k], q.x, fmaf(m2y[k], q.y, qqa));
            float tb = fmaf(m2x[k], q.z, fmaf(m2y[k], q.w, qqb));
            mn[k] = fminf(mn[k], fminf(ta, tb));   // v_min3_f32
        }
    }

    // ---- Funnel: coalesced fire-and-forget atomicMin into pmin ----
    int* gp = pmin + ((size_t)g << 12);            // this group's 4096 entries
    #pragma unroll
    for (int k = 0; k < IB; ++k)
        atomicMin(&gp[i0 + k * TPB], __float_as_int(mn[k] + pp[k]));

    __threadfence();                               // atomics drained before count
    if (t == 0) {
        int old = atomicAdd(&cnt[g], 1);
        sflag = (old == GBLOCKS - 1);
    }
    __syncthreads();
    if (!sflag) return;

    // ---- Stage 2 (one block per group): max over the 4096 mins ----
    float mx = -3.402823466e38f;
    #pragma unroll
    for (int k = 0; k < 16; ++k) {
        int v = atomicMin(&gp[t + k * TPB], 0x7FFFFFFF);   // coherent read (no-op write)
        mx = fmaxf(mx, __int_as_float(v));
    }
    #pragma unroll
    for (int off = 32; off > 0; off >>= 1)
        mx = fmaxf(mx, __shfl_down(mx, off, 64));
    if ((t & 63) == 0) sred[t >> 6] = mx;
    __syncthreads();
    if (t == 0) {
        float bm = sred[0];
        #pragma unroll
        for (int w = 1; w < TPB / 64; ++w) bm = fmaxf(bm, sred[w]);
        atomicMax(&slots[g], __float_as_int(fmaxf(bm, 0.f)));  // publish h^2(dir,b)
        __threadfence();
        int old2 = atomicAdd(cnt2, 1);
        sflag2 = (old2 == NGROUP - 1);
    }
    __syncthreads();
    if (!sflag2) return;

    // ---- Stage 3 (exactly one block): final scalar ----
    __shared__ float sh2[NGROUP];
    if (t < NGROUP) sh2[t] = __int_as_float(atomicMax(&slots[t], 0));
    __syncthreads();
    if (t == 0) {
        float s = 0.f;
        #pragma unroll
        for (int bb = 0; bb < B; ++bb)
            s += sqrtf(fmaxf(sh2[bb], sh2[B + bb]));
        out[0] = s * (1.0f / B);
    }
}

extern "C" void kernel_launch(void* const* d_in, const int* in_sizes, int n_in,
                              void* d_out, int out_size, void* d_ws, size_t ws_size,
                              hipStream_t stream) {
    const float* pred   = (const float*)d_in[0];
    const float* target = (const float*)d_in[1];
    float* out = (float*)d_out;

    int* slots = (int*)d_ws;                       // [16]
    int* cnt   = (int*)d_ws + 16;                  // [16]
    int* cnt2  = (int*)d_ws + 32;                  // [1]
    int* pmin  = (int*)((char*)d_ws + 1024);       // [2][B][N] = 256 KB

    hipMemsetAsync(d_ws, 0, 256, stream);                          // counters+slots
    hipMemsetAsync(pmin, 0x7F, (size_t)2 * B * N * sizeof(int), stream);  // +3.39e38

    dim3 g1(GBLOCKS, B, 2);      // 1024 blocks -> 4 blocks/CU, 16 waves/CU
    hk_main<<<g1, TPB, 0, stream>>>(pred, target, pmin, cnt, slots, cnt2, out);
}